// Round 3
// baseline (252.676 us; speedup 1.0000x reference)
//
#include <hip/hip_runtime.h>
#include <hip/hip_bf16.h>
#include <math.h>

// B=2, T=2048, D=1024, H=16, hd=64, ALPHA=1 (decay = -(i-j))
// Pipeline: fused cast f32->bf16 -> fused QKV NT-GEMM (V transposed) -> flash attn -> out GEMM (f32)

typedef __bf16 bf16_t;
typedef bf16_t bf16x8 __attribute__((ext_vector_type(8)));
typedef bf16_t bf16x4 __attribute__((ext_vector_type(4)));
typedef float  floatx4 __attribute__((ext_vector_type(4)));

#define LOG2E 1.44269504088896f

__device__ __forceinline__ void async16(const bf16_t* g, bf16_t* l) {
  __builtin_amdgcn_global_load_lds(
      (const __attribute__((address_space(1))) unsigned int*)g,
      (__attribute__((address_space(3))) unsigned int*)l, 16, 0, 0);
}

// ---------------- fused cast kernel ----------------
__global__ void castall(const float* __restrict__ x,
                        const float* __restrict__ wq, const float* __restrict__ wk,
                        const float* __restrict__ wv, const float* __restrict__ wo,
                        bf16_t* __restrict__ xb, bf16_t* __restrict__ wdst) {
  int i = blockIdx.x * blockDim.x + threadIdx.x;  // 0 .. 2097151
  const float* src;
  bf16_t* dst;
  if (i < 1048576) {
    src = x + (size_t)i * 4;
    dst = xb + (size_t)i * 4;
  } else {
    int i2 = i - 1048576;
    int wsel = i2 >> 18;
    int off = i2 & 262143;
    const float* wsrc = (wsel == 0) ? wq : (wsel == 1) ? wk : (wsel == 2) ? wv : wo;
    src = wsrc + (size_t)off * 4;
    dst = wdst + (size_t)i2 * 4;
  }
  const float4 f = *(const float4*)src;
  bf16x4 o;
  o[0] = (bf16_t)f.x; o[1] = (bf16_t)f.y; o[2] = (bf16_t)f.z; o[3] = (bf16_t)f.w;
  *(bf16x4*)dst = o;
}

// ---------------- NT GEMM: C[m,n] = sum_k A[m,k]*W[n,k] + bias[n] ----------------
#define BK 32

template<bool OUT_F32>
__global__ __launch_bounds__(256, 2)
void gemm_nt(const bf16_t* __restrict__ A,
             const bf16_t* __restrict__ W0, const bf16_t* __restrict__ W1,
             const bf16_t* __restrict__ W2,
             const float* __restrict__ b0, const float* __restrict__ b1,
             const float* __restrict__ b2,
             bf16_t* O0, bf16_t* O1, bf16_t* O2, float* OF,
             int nbPer, int vTrans)
{
  __shared__ __align__(16) bf16_t As[128 * BK];
  __shared__ __align__(16) bf16_t Bs[128 * BK];
  const int t = threadIdx.x, w = t >> 6, lane = t & 63;
  const int l15 = lane & 15, q4 = lane >> 4;
  const int wsel = blockIdx.x / nbPer, nb = blockIdx.x % nbPer;
  const bf16_t* Wm = (wsel == 0) ? W0 : ((wsel == 1) ? W1 : W2);
  const float* bias = (wsel == 0) ? b0 : ((wsel == 1) ? b1 : b2);
  bf16_t* Om = (wsel == 0) ? O0 : ((wsel == 1) ? O1 : O2);
  const int m0 = blockIdx.y * 128;
  const int n0 = nb * 128;
  const int wm = (w >> 1) * 64, wn = (w & 1) * 64;

  floatx4 acc[4][4];
#pragma unroll
  for (int mi = 0; mi < 4; ++mi)
#pragma unroll
    for (int ni = 0; ni < 4; ++ni) acc[mi][ni] = (floatx4){0.f, 0.f, 0.f, 0.f};

  const int ch0 = w * 128 + lane;
  for (int k0 = 0; k0 < 1024; k0 += BK) {
#pragma unroll
    for (int c = 0; c < 2; ++c) {
      int chunk = ch0 + c * 64;           // 0..511
      int row = chunk >> 2, seg = chunk & 3;
      async16(A  + (size_t)(m0 + row) * 1024 + k0 + seg * 8, &As[chunk * 8]);
      async16(Wm + (size_t)(n0 + row) * 1024 + k0 + seg * 8, &Bs[chunk * 8]);
    }
    __syncthreads();

    bf16x8 af[4], bfr[4];
#pragma unroll
    for (int i = 0; i < 4; ++i) {
      af[i]  = *(const bf16x8*)&As[(wm + i * 16 + l15) * BK + q4 * 8];
      bfr[i] = *(const bf16x8*)&Bs[(wn + i * 16 + l15) * BK + q4 * 8];
    }
#pragma unroll
    for (int mi = 0; mi < 4; ++mi)
#pragma unroll
      for (int ni = 0; ni < 4; ++ni)
        acc[mi][ni] = __builtin_amdgcn_mfma_f32_16x16x32_bf16(af[mi], bfr[ni], acc[mi][ni], 0, 0, 0);
    __syncthreads();
  }

  // epilogue; C/D layout: col = lane&15, row = (lane>>4)*4 + reg
#pragma unroll
  for (int mi = 0; mi < 4; ++mi) {
#pragma unroll
    for (int ni = 0; ni < 4; ++ni) {
      const int col = n0 + wn + ni * 16 + l15;
      const float bv = bias[col];
      if (OUT_F32) {
#pragma unroll
        for (int r = 0; r < 4; ++r) {
          int row = m0 + wm + mi * 16 + q4 * 4 + r;
          OF[(size_t)row * 1024 + col] = acc[mi][ni][r] + bv;
        }
      } else if (vTrans && wsel == 2) {
        // V transposed: Vt[b][d][t]; lane holds 4 consecutive t -> 8B store
        int rowg = m0 + wm + mi * 16 + q4 * 4;
        int bb = rowg >> 11, tt = rowg & 2047;
        bf16x4 pk;
#pragma unroll
        for (int r = 0; r < 4; ++r) pk[r] = (bf16_t)(acc[mi][ni][r] + bv);
        *(bf16x4*)(Om + (size_t)(bb * 1024 + col) * 2048 + tt) = pk;
      } else {
#pragma unroll
        for (int r = 0; r < 4; ++r) {
          int row = m0 + wm + mi * 16 + q4 * 4 + r;
          Om[(size_t)row * 1024 + col] = (bf16_t)(acc[mi][ni][r] + bv);
        }
      }
    }
  }
}

// ---------------- flash attention: wave-autonomous, barrier-free ----------------
// Each wave owns 32 q rows (2 strips of 16). K/Q/V fragments loaded DIRECTLY
// global->VGPR (16B contiguous; identical addrs across the block's 4 waves -> L1 hits).
// Computes S^T = K.Q^T so P's C-layout gives each lane 4 contiguous j -> b64 LDS
// writes for the P transpose; l obtained via an extra MFMA P.ones whose C-layout
// matches o_acc's i-mapping (no shuffles, exactly consistent with PV).
// Fixed-max softmax (scores bounded); no __syncthreads anywhere.
__global__ __launch_bounds__(256, 2)
void attn_kernel(const bf16_t* __restrict__ Qb, const bf16_t* __restrict__ Kb,
                 const bf16_t* __restrict__ Vt, bf16_t* __restrict__ AO)
{
  __shared__ __align__(16) bf16_t Ps[4][2][16][72];  // [wave][strip][i][j+pad]

  const int t = threadIdx.x, w = t >> 6, lane = t & 63;
  const int l15 = lane & 15, q4 = lane >> 4;
  // heavy blocks (qq=15) first
  const int bh = blockIdx.x & 31, qz = blockIdx.x >> 5;
  const int qq = 15 - qz;
  const int b = bh >> 4, h = bh & 15;
  const int r0 = qq * 128 + w * 32;          // wave's first q row
  const int nIter = (r0 + 31) / 64 + 1;

  const float C1 = 0.125f * LOG2E;           // score scale (1/sqrt(64)) * log2e
  const float CL = LOG2E;                    // decay * log2e

  // Q fragments: B-frag (n=i=l15, k=d=kk*32+q4*8+e) -> contiguous 16B
  bf16x8 qf[2][2];
#pragma unroll
  for (int s = 0; s < 2; ++s) {
    const bf16_t* qp = Qb + ((size_t)(b * 2048 + r0 + s * 16 + l15)) * 1024 + h * 64 + q4 * 8;
    qf[s][0] = *(const bf16x8*)qp;
    qf[s][1] = *(const bf16x8*)(qp + 32);
  }

  // K row pointers (j advances 64/iter -> +65536 elems), V-t pointers (+64 elems)
  const bf16_t* kp[4];
  const bf16_t* vp[4];
#pragma unroll
  for (int mt = 0; mt < 4; ++mt)
    kp[mt] = Kb + ((size_t)(b * 2048 + mt * 16 + l15)) * 1024 + h * 64 + q4 * 8;
#pragma unroll
  for (int dt = 0; dt < 4; ++dt)
    vp[dt] = Vt + ((size_t)(b * 1024 + h * 64 + dt * 16 + l15)) * 2048 + q4 * 8;

  floatx4 o_acc[2][4], lsum[2];
#pragma unroll
  for (int s = 0; s < 2; ++s) {
    lsum[s] = (floatx4){0.f, 0.f, 0.f, 0.f};
#pragma unroll
    for (int dt = 0; dt < 4; ++dt) o_acc[s][dt] = (floatx4){0.f, 0.f, 0.f, 0.f};
  }
  bf16x8 ones;
#pragma unroll
  for (int e = 0; e < 8; ++e) ones[e] = (bf16_t)1.0f;

  // decay base (j - i)*CL for the (mt=0,r=0) element, and int mask threshold
  float d0[2];
  int rel[2];
#pragma unroll
  for (int s = 0; s < 2; ++s) {
    int i = r0 + s * 16 + l15;
    d0[s] = (float)(q4 * 4 - i) * CL;   // j0 = 0
    rel[s] = i - q4 * 4;
  }

  for (int jt = 0; jt < nIter; ++jt) {
    const int j0 = jt * 64;
    // ---- fragment loads (all issued up front; vf flight hidden by QK+softmax)
    bf16x8 kf[4][2], vf[4][2];
#pragma unroll
    for (int mt = 0; mt < 4; ++mt) {
      kf[mt][0] = *(const bf16x8*)kp[mt];
      kf[mt][1] = *(const bf16x8*)(kp[mt] + 32);
      kp[mt] += 65536;
    }
#pragma unroll
    for (int dt = 0; dt < 4; ++dt) {
      vf[dt][0] = *(const bf16x8*)vp[dt];
      vf[dt][1] = *(const bf16x8*)(vp[dt] + 32);
      vp[dt] += 64;
    }

    // ---- S^T = K.Q^T : A=kf (m=j), B=qf (n=i); C: col=i=l15, row=j=q4*4+r
    floatx4 s4[2][4];
#pragma unroll
    for (int s = 0; s < 2; ++s)
#pragma unroll
      for (int mt = 0; mt < 4; ++mt) s4[s][mt] = (floatx4){0.f, 0.f, 0.f, 0.f};
#pragma unroll
    for (int s = 0; s < 2; ++s)
#pragma unroll
      for (int mt = 0; mt < 4; ++mt)
#pragma unroll
        for (int kk = 0; kk < 2; ++kk)
          s4[s][mt] = __builtin_amdgcn_mfma_f32_16x16x32_bf16(kf[mt][kk], qf[s][kk], s4[s][mt], 0, 0, 0);

    // ---- softmax numerator p = exp2((s/8 + (j-i)) * log2e), causal zeroing
#pragma unroll
    for (int s = 0; s < 2; ++s) {
      const bool needMask = (j0 + 63) > (r0 + s * 16);
#pragma unroll
      for (int mt = 0; mt < 4; ++mt) {
        bf16x4 pk;
#pragma unroll
        for (int r = 0; r < 4; ++r) {
          float arg = fmaf(s4[s][mt][r], C1, d0[s] + (float)(mt * 16 + r) * CL);
          float p = exp2f(arg);
          if (needMask && (mt * 16 + r) > rel[s]) p = 0.f;
          pk[r] = (bf16_t)p;
        }
        *(bf16x4*)&Ps[w][s][l15][mt * 16 + q4 * 4] = pk;  // 4 contiguous j
      }
      d0[s] += 64.0f * CL;
      rel[s] -= 64;
    }

    __builtin_amdgcn_s_waitcnt(0xC07F);  // lgkmcnt(0): own-wave P writes visible

    // ---- O += P.V  and  l += P.ones  (A=pf m=i, k=j)
    bf16x8 pf[2][2];
#pragma unroll
    for (int s = 0; s < 2; ++s)
#pragma unroll
      for (int kk = 0; kk < 2; ++kk)
        pf[s][kk] = *(const bf16x8*)&Ps[w][s][l15][kk * 32 + q4 * 8];
#pragma unroll
    for (int s = 0; s < 2; ++s)
#pragma unroll
      for (int kk = 0; kk < 2; ++kk)
        lsum[s] = __builtin_amdgcn_mfma_f32_16x16x32_bf16(pf[s][kk], ones, lsum[s], 0, 0, 0);
#pragma unroll
    for (int s = 0; s < 2; ++s)
#pragma unroll
      for (int dt = 0; dt < 4; ++dt)
#pragma unroll
        for (int kk = 0; kk < 2; ++kk)
          o_acc[s][dt] = __builtin_amdgcn_mfma_f32_16x16x32_bf16(pf[s][kk], vf[dt][kk], o_acc[s][dt], 0, 0, 0);
  }

  // ---- normalize & store: o_acc C-layout: row=i=q4*4+r, col=d=l15; lsum same rows
#pragma unroll
  for (int s = 0; s < 2; ++s) {
    floatx4 inv;
#pragma unroll
    for (int r = 0; r < 4; ++r) inv[r] = 1.0f / lsum[s][r];
#pragma unroll
    for (int dt = 0; dt < 4; ++dt)
#pragma unroll
      for (int r = 0; r < 4; ++r) {
        int i = r0 + s * 16 + q4 * 4 + r;
        AO[((size_t)(b * 2048 + i)) * 1024 + h * 64 + dt * 16 + l15] =
            (bf16_t)(o_acc[s][dt][r] * inv[r]);
      }
  }
}

// ---------------- launch ----------------
extern "C" void kernel_launch(void* const* d_in, const int* in_sizes, int n_in,
                              void* d_out, int out_size, void* d_ws, size_t ws_size,
                              hipStream_t stream) {
  const float* x  = (const float*)d_in[0];
  const float* Wq = (const float*)d_in[1];
  const float* bq = (const float*)d_in[2];
  const float* Wk = (const float*)d_in[3];
  const float* bk = (const float*)d_in[4];
  const float* Wv = (const float*)d_in[5];
  const float* bv = (const float*)d_in[6];
  const float* Wo = (const float*)d_in[7];
  const float* bo = (const float*)d_in[8];

  char* ws = (char*)d_ws;                      // needs >= 48 MB
  bf16_t* xb  = (bf16_t*)(ws);                 //  8 MB
  bf16_t* wqb = (bf16_t*)(ws + (8u  << 20));   //  2 MB (wq..wo contiguous)
  bf16_t* wkb = (bf16_t*)(ws + (10u << 20));
  bf16_t* wvb = (bf16_t*)(ws + (12u << 20));
  bf16_t* wob = (bf16_t*)(ws + (14u << 20));
  bf16_t* Qb  = (bf16_t*)(ws + (16u << 20));   //  8 MB  [b,t,h,d]
  bf16_t* Kb  = (bf16_t*)(ws + (24u << 20));   //  8 MB  [b,t,h,d]
  bf16_t* Vtb = (bf16_t*)(ws + (32u << 20));   //  8 MB  [b,h*d,t]
  bf16_t* AOb = (bf16_t*)(ws + (40u << 20));   //  8 MB  [b,t,h,d]

  castall<<<8192, 256, 0, stream>>>(x, Wq, Wk, Wv, Wo, xb, wqb);

  gemm_nt<false><<<dim3(24, 32), 256, 0, stream>>>(
      xb, wqb, wkb, wvb, bq, bk, bv, Qb, Kb, Vtb, nullptr, 8, 1);

  attn_kernel<<<512, 256, 0, stream>>>(Qb, Kb, Vtb, AOb);

  gemm_nt<true><<<dim3(8, 32), 256, 0, stream>>>(
      AOb, wob, wob, wob, bo, bo, bo, nullptr, nullptr, nullptr, (float*)d_out, 8, 0);
}